// Round 10
// baseline (15740.950 us; speedup 1.0000x reference)
//
#include <hip/hip_runtime.h>
#include <hip/hip_bf16.h>
#include <math.h>
#include <stdint.h>

using bf16 = __hip_bfloat16;
typedef __attribute__((ext_vector_type(8))) short short8;   // 8 bf16 (MFMA A/B frag)
typedef __attribute__((ext_vector_type(4))) float floatx4;  // MFMA C/D frag (f32)
typedef __attribute__((ext_vector_type(4))) int int4v;      // i8 K=64 frag / i32 acc

typedef const __attribute__((address_space(1))) void* gptr_t;
typedef __attribute__((address_space(3))) void* lptr_t;

__device__ __forceinline__ void load_lds16(const void* g, void* l) {
    __builtin_amdgcn_global_load_lds((gptr_t)(uintptr_t)g, (lptr_t)(uintptr_t)l, 16, 0, 0);
}

// wait until at most N vector-memory ops outstanding (gfx9 6-bit vmcnt split)
#define WAIT_VM(n) __builtin_amdgcn_s_waitcnt(0x0F70 | ((n) & 15) | (((n) >> 4) << 14))

__device__ __forceinline__ float fast_tanh(float x) {
    float e = __expf(2.f * x);
    return 1.f - 2.f / (e + 1.f);
}

// ---------------------------------------------------------------------------
// Grid barrier for a 512-block persistent kernel (all blocks co-resident by
// construction: 64 KB LDS + launch_bounds(256,2) -> exactly 2 blocks/CU).
// Hierarchical monotonic counters: 8 per-XCD partials (own cache lines), last
// arriver of each XCD bumps master; everyone spins on master == 8*bar.
// Monotonic => no reset race. threadfence gives agent-scope rel/acq.
// ---------------------------------------------------------------------------
__device__ __forceinline__ void gsync(unsigned* part, unsigned* master, int bar, int b) {
    __syncthreads();
    if (threadIdx.x == 0) {
        __threadfence();   // release: publish this block's writes
        unsigned* p = part + (b & 7) * 32;
        unsigned old = __hip_atomic_fetch_add(p, 1u, __ATOMIC_ACQ_REL,
                                              __HIP_MEMORY_SCOPE_AGENT);
        if (old == (unsigned)(64 * bar - 1))
            __hip_atomic_fetch_add(master, 1u, __ATOMIC_ACQ_REL,
                                   __HIP_MEMORY_SCOPE_AGENT);
        while (__hip_atomic_load(master, __ATOMIC_ACQUIRE,
                                 __HIP_MEMORY_SCOPE_AGENT) < (unsigned)(8 * bar))
            __builtin_amdgcn_s_sleep(2);
        __threadfence();   // acquire: invalidate stale lines before reads
    }
    __syncthreads();
}

// ---------------------------------------------------------------------------
// Phase 1 (r9 gemm_tanh4 verbatim): x1i = i8(tanh(x0·W1^T + b1) * 127)
// bf16 core, 128x128 tile, 4 waves, dbuf 2x(16+16) KB, WAIT_VM(8), XCD swizzle.
// ---------------------------------------------------------------------------
__device__ void phase_l1(int b, char* smem, const bf16* __restrict__ A,
                         const bf16* __restrict__ W, const float* __restrict__ bias,
                         int8_t* __restrict__ out) {
    constexpr int MT = 4, NT = 4;
    const int K = 512, N = 1024;
    bf16* lA = (bf16*)smem;              // [2][128*64]
    bf16* lB = (bf16*)(smem + 32768);    // [2][128*64]

    const int xcd = b & 7, j = b >> 3;
    const int bx = j & 7;
    const int by = xcd + 8 * (j >> 3);

    const int tid  = threadIdx.x;
    const int lane = tid & 63;
    const int w    = tid >> 6;
    const int wr   = w >> 1, wc = w & 1;
    const int quad = lane >> 4, l16 = lane & 15;
    const int brow = by * 128, bcol = bx * 128;

    const bf16* gA[4]; const bf16* gW[4]; int lq[4];
#pragma unroll
    for (int jj = 0; jj < 4; ++jj) {
        const int q = tid + jj * 256;
        const int r = q >> 3, s = (q & 7) ^ (r & 7);
        gA[jj] = A + (size_t)(brow + r) * K + s * 8;
        gW[jj] = W + (size_t)(bcol + r) * K + s * 8;
        lq[jj] = q * 8;
    }

    floatx4 acc[MT][NT];
    const floatx4 zero = {0.f, 0.f, 0.f, 0.f};
#pragma unroll
    for (int mt = 0; mt < MT; ++mt)
#pragma unroll
        for (int nt = 0; nt < NT; ++nt) acc[mt][nt] = zero;

    const int arow0 = wr * 64 + l16;
    const int brow0 = wc * 64 + l16;
    const int x7 = l16 & 7;

    const int nIter = K / 64;  // 8
#pragma unroll
    for (int jj = 0; jj < 4; ++jj) load_lds16(gA[jj], lA + lq[jj]);
#pragma unroll
    for (int jj = 0; jj < 4; ++jj) load_lds16(gW[jj], lB + lq[jj]);

    for (int kt = 0; kt < nIter; ++kt) {
        const int cur = kt & 1;
        if (kt + 1 < nIter) {
#pragma unroll
            for (int jj = 0; jj < 4; ++jj)
                load_lds16(gA[jj] + (kt + 1) * 64, lA + (cur ^ 1) * 8192 + lq[jj]);
#pragma unroll
            for (int jj = 0; jj < 4; ++jj)
                load_lds16(gW[jj] + (kt + 1) * 64, lB + (cur ^ 1) * 8192 + lq[jj]);
            WAIT_VM(8);
        } else {
            WAIT_VM(0);
        }
        __builtin_amdgcn_s_barrier();

#pragma unroll
        for (int kk = 0; kk < 2; ++kk) {
            const int sw = ((kk * 4 + quad) ^ x7) * 8;
            short8 af[MT], bfr[NT];
#pragma unroll
            for (int mt = 0; mt < MT; ++mt)
                af[mt] = *(const short8*)(lA + cur * 8192 + (arow0 + mt * 16) * 64 + sw);
#pragma unroll
            for (int nt = 0; nt < NT; ++nt)
                bfr[nt] = *(const short8*)(lB + cur * 8192 + (brow0 + nt * 16) * 64 + sw);
#pragma unroll
            for (int mt = 0; mt < MT; ++mt)
#pragma unroll
                for (int nt = 0; nt < NT; ++nt)
                    acc[mt][nt] = __builtin_amdgcn_mfma_f32_16x16x32_bf16(
                        af[mt], bfr[nt], acc[mt][nt], 0, 0, 0);
        }
        __builtin_amdgcn_s_barrier();
    }

    const int m0 = brow + wr * 64 + quad * 4;
    const int n0 = bcol + wc * 64 + l16;
#pragma unroll
    for (int mt = 0; mt < MT; ++mt)
#pragma unroll
        for (int nt = 0; nt < NT; ++nt) {
            const int n = n0 + nt * 16;
            const float bb = bias[n];
#pragma unroll
            for (int i = 0; i < 4; ++i) {
                const int m = m0 + mt * 16 + i;
                const float t = fast_tanh(acc[mt][nt][i] + bb);
                out[(size_t)m * N + n] = (int8_t)__float2int_rn(t * 127.f);
            }
        }
}

// ---------------------------------------------------------------------------
// Phase 2 (r9 gemm_tanh_i8 verbatim): x2b = bf16(tanh(acc*dq[n] + b2))
// i8 core, K=1024, 128-B rows, XOR-8 on 16-B chunks, dbuf 2x(16+16) KB.
// ---------------------------------------------------------------------------
__device__ void phase_l2(int b, char* smem, const int8_t* __restrict__ A,
                         const int8_t* __restrict__ W, const float* __restrict__ dq,
                         const float* __restrict__ bias, bf16* __restrict__ out) {
    constexpr int MT = 4, NT = 4;
    const int K = 1024, N = 1024;
    int8_t* lA = (int8_t*)smem;             // [2][128*128]
    int8_t* lB = (int8_t*)(smem + 32768);   // [2][128*128]

    const int xcd = b & 7, j = b >> 3;
    const int bx = j & 7;
    const int by = xcd + 8 * (j >> 3);

    const int tid  = threadIdx.x;
    const int lane = tid & 63;
    const int w    = tid >> 6;
    const int wr   = w >> 1, wc = w & 1;
    const int quad = lane >> 4, l16 = lane & 15;
    const int brow = by * 128, bcol = bx * 128;

    const int8_t* gA[4]; const int8_t* gW[4]; int lq[4];
#pragma unroll
    for (int jj = 0; jj < 4; ++jj) {
        const int q = tid + jj * 256;
        const int r = q >> 3, s = (q & 7) ^ (r & 7);
        gA[jj] = A + (size_t)(brow + r) * K + s * 16;
        gW[jj] = W + (size_t)(bcol + r) * K + s * 16;
        lq[jj] = q * 16;
    }

    int4v acc[MT][NT];
    const int4v izero = {0, 0, 0, 0};
#pragma unroll
    for (int mt = 0; mt < MT; ++mt)
#pragma unroll
        for (int nt = 0; nt < NT; ++nt) acc[mt][nt] = izero;

    const int arow0 = wr * 64 + l16;
    const int brow0 = wc * 64 + l16;
    const int x7 = l16 & 7;

    const int nIter = K / 128;  // 8
#pragma unroll
    for (int jj = 0; jj < 4; ++jj) load_lds16(gA[jj], lA + lq[jj]);
#pragma unroll
    for (int jj = 0; jj < 4; ++jj) load_lds16(gW[jj], lB + lq[jj]);

    for (int kt = 0; kt < nIter; ++kt) {
        const int cur = kt & 1;
        if (kt + 1 < nIter) {
#pragma unroll
            for (int jj = 0; jj < 4; ++jj)
                load_lds16(gA[jj] + (kt + 1) * 128, lA + (cur ^ 1) * 16384 + lq[jj]);
#pragma unroll
            for (int jj = 0; jj < 4; ++jj)
                load_lds16(gW[jj] + (kt + 1) * 128, lB + (cur ^ 1) * 16384 + lq[jj]);
            WAIT_VM(8);
        } else {
            WAIT_VM(0);
        }
        __builtin_amdgcn_s_barrier();

#pragma unroll
        for (int kk = 0; kk < 2; ++kk) {
            const int sw = ((kk * 4 + quad) ^ x7) * 16;
            int4v af[MT], bfr[NT];
#pragma unroll
            for (int mt = 0; mt < MT; ++mt)
                af[mt] = *(const int4v*)(lA + cur * 16384 + (arow0 + mt * 16) * 128 + sw);
#pragma unroll
            for (int nt = 0; nt < NT; ++nt)
                bfr[nt] = *(const int4v*)(lB + cur * 16384 + (brow0 + nt * 16) * 128 + sw);
#pragma unroll
            for (int mt = 0; mt < MT; ++mt)
#pragma unroll
                for (int nt = 0; nt < NT; ++nt)
                    acc[mt][nt] = __builtin_amdgcn_mfma_i32_16x16x64_i8(
                        af[mt], bfr[nt], acc[mt][nt], 0, 0, 0);
        }
        __builtin_amdgcn_s_barrier();
    }

    const int m0 = brow + wr * 64 + quad * 4;
    const int n0 = bcol + wc * 64 + l16;
#pragma unroll
    for (int mt = 0; mt < MT; ++mt)
#pragma unroll
        for (int nt = 0; nt < NT; ++nt) {
            const int n = n0 + nt * 16;
            const float bb = bias[n];
            const float dqn = dq[n];
#pragma unroll
            for (int i = 0; i < 4; ++i) {
                const int m = m0 + mt * 16 + i;
                out[(size_t)m * N + n] =
                    __float2bfloat16(fast_tanh((float)acc[mt][nt][i] * dqn + bb));
            }
        }
}

// ---------------------------------------------------------------------------
// Phase 3 (r9 gemm_k verbatim, one 64x64 tile): RK4-fused L3 GEMM, K=1024.
// Single-buffered 2-barrier core (memory-bound; ~its floor). 16 KB LDS.
// ---------------------------------------------------------------------------
__device__ void phase_l3_tile(int T, char* smem, const bf16* __restrict__ A,
                              const bf16* __restrict__ W, const float* __restrict__ bias,
                              bf16* __restrict__ kacc, const bf16* __restrict__ hb_src,
                              const float* __restrict__ h_src, float* __restrict__ h_out,
                              bf16* __restrict__ hb_out, bf16* __restrict__ x0_out,
                              const float* __restrict__ temb, float alpha, float dt6,
                              int mode) {
    constexpr int MT = 2, NT = 2;
    const int K = 1024;
    bf16* lA = (bf16*)smem;             // 64*64 bf16 = 8 KB
    bf16* lB = (bf16*)(smem + 8192);    // 8 KB

    const int xcd = T & 7, j = T >> 3;
    const int bx = j & 7;
    const int by = xcd + 8 * (j >> 3);
    const int brow = by * 64, bcol = bx * 64;

    const int tid  = threadIdx.x;
    const int lane = tid & 63;
    const int w    = tid >> 6;
    const int wr   = w >> 1, wc = w & 1;
    const int quad = lane >> 4, l16 = lane & 15;

    const bf16* gA[2]; const bf16* gW[2];
    bf16* lAd[2]; bf16* lBd[2];
#pragma unroll
    for (int jj = 0; jj < 2; ++jj) {
        const int q = tid + jj * 256;
        const int r = q >> 3, s = (q & 7) ^ (r & 7);
        gA[jj]  = A + (size_t)(brow + r) * K + s * 8;
        gW[jj]  = W + (size_t)(bcol + r) * K + s * 8;
        lAd[jj] = lA + q * 8;
        lBd[jj] = lB + q * 8;
    }

    floatx4 acc[MT][NT];
    const floatx4 zero = {0.f, 0.f, 0.f, 0.f};
#pragma unroll
    for (int mt = 0; mt < MT; ++mt)
#pragma unroll
        for (int nt = 0; nt < NT; ++nt) acc[mt][nt] = zero;

    const int arow = wr * 32 + l16;
    const int brw  = wc * 32 + l16;
    const int x7   = l16 & 7;

    const int nIter = K / 64;
    for (int kt = 0; kt < nIter; ++kt) {
#pragma unroll
        for (int jj = 0; jj < 2; ++jj) load_lds16(gA[jj], lAd[jj]);
#pragma unroll
        for (int jj = 0; jj < 2; ++jj) load_lds16(gW[jj], lBd[jj]);
        __syncthreads();

#pragma unroll
        for (int kk = 0; kk < 2; ++kk) {
            const int sw = ((kk * 4 + quad) ^ x7) * 8;
            short8 af[MT], bfr[NT];
#pragma unroll
            for (int mt = 0; mt < MT; ++mt)
                af[mt] = *(const short8*)(lA + (arow + mt * 16) * 64 + sw);
#pragma unroll
            for (int nt = 0; nt < NT; ++nt)
                bfr[nt] = *(const short8*)(lB + (brw + nt * 16) * 64 + sw);
#pragma unroll
            for (int mt = 0; mt < MT; ++mt)
#pragma unroll
                for (int nt = 0; nt < NT; ++nt)
                    acc[mt][nt] = __builtin_amdgcn_mfma_f32_16x16x32_bf16(
                        af[mt], bfr[nt], acc[mt][nt], 0, 0, 0);
        }
        __syncthreads();

#pragma unroll
        for (int jj = 0; jj < 2; ++jj) gA[jj] += 64;
#pragma unroll
        for (int jj = 0; jj < 2; ++jj) gW[jj] += 64;
    }

    const int m0 = brow + wr * 32 + quad * 4;
    const int n0 = bcol + wc * 32 + l16;
#pragma unroll
    for (int mt = 0; mt < MT; ++mt)
#pragma unroll
        for (int nt = 0; nt < NT; ++nt) {
            const int n = n0 + nt * 16;
            const float bb = bias[n];
            const float te = temb[n];
#pragma unroll
            for (int i = 0; i < 4; ++i) {
                const int m = m0 + mt * 16 + i;
                const size_t idx = (size_t)m * 512 + n;
                const float kv = acc[mt][nt][i] + bb;
                if (mode == 0) {
                    kacc[idx] = __float2bfloat16(kv);
                    x0_out[idx] = __float2bfloat16(
                        __bfloat162float(hb_src[idx]) + alpha * kv + te);
                } else if (mode == 1) {
                    kacc[idx] = __float2bfloat16(__bfloat162float(kacc[idx]) + 2.f * kv);
                    x0_out[idx] = __float2bfloat16(
                        __bfloat162float(hb_src[idx]) + alpha * kv + te);
                } else {
                    const float hn = h_src[idx] + dt6 * (__bfloat162float(kacc[idx]) + kv);
                    h_out[idx] = hn;
                    hb_out[idx] = __float2bfloat16(hn);
                    if (x0_out) x0_out[idx] = __float2bfloat16(hn + te);
                }
            }
        }
}

// ---------------------------------------------------------------------------
// Persistent kernel: all 10 RK4 steps x 4 evals x 3 GEMMs, grid barriers
// between phases. 512 blocks, 64 KB LDS, 2 blocks/CU -> all co-resident.
// ---------------------------------------------------------------------------
__global__ void __launch_bounds__(256, 2)
ode_persistent(const bf16* __restrict__ W1b, const int8_t* __restrict__ W2i,
               const float* __restrict__ dq, const bf16* __restrict__ W3b,
               const float* __restrict__ b1, const float* __restrict__ b2,
               const float* __restrict__ b3, const float* __restrict__ temb,
               bf16* __restrict__ x0b, int8_t* __restrict__ x1i,
               bf16* __restrict__ x2b, bf16* __restrict__ kacc,
               bf16* __restrict__ hb, const float* __restrict__ h_in,
               float* __restrict__ hbuf, unsigned* __restrict__ part,
               unsigned* __restrict__ master) {
    __shared__ alignas(16) char smem[65536];
    const int b = blockIdx.x;
    const float dt = 0.1f;
    int bar = 0;

    for (int s = 0; s < 10; ++s) {
        const float* hs = (s == 0) ? h_in : hbuf;
        const float* tmid = temb + (size_t)(2 * s + 1) * 512;
        const float* tend = temb + (size_t)(2 * s + 2) * 512;
        for (int e = 0; e < 4; ++e) {
            phase_l1(b, smem, x0b, W1b, b1, x1i);
            gsync(part, master, ++bar, b);
            phase_l2(b, smem, x1i, W2i, dq, b2, x2b);
            gsync(part, master, ++bar, b);
            // phase 3: two 64x64 tiles per block (1024 tiles / 512 blocks)
            const float* te; float alpha, dt6; int mode;
            bf16* x0o = x0b;
            if (e == 0)      { mode = 0; alpha = dt * 0.5f; dt6 = 0.f; te = tmid; }
            else if (e == 1) { mode = 1; alpha = dt * 0.5f; dt6 = 0.f; te = tmid; }
            else if (e == 2) { mode = 1; alpha = dt;        dt6 = 0.f; te = tend; }
            else             { mode = 2; alpha = 0.f; dt6 = dt / 6.f; te = tend;
                               if (s == 9) x0o = nullptr; }
#pragma unroll
            for (int t = 0; t < 2; ++t)
                phase_l3_tile(b + 512 * t, smem, x2b, W3b, b3, kacc, hb, hs,
                              hbuf, hb, x0o, te, alpha, dt6, mode);
            gsync(part, master, ++bar, b);
        }
    }
}

// ------------------------------ setup kernels ------------------------------
__global__ void f2b_kern(const float* __restrict__ src, bf16* __restrict__ dst, int n) {
    const int i = blockIdx.x * blockDim.x + threadIdx.x;
    if (i < n) dst[i] = __float2bfloat16(src[i]);
}

__global__ void quantW2_row(const float* __restrict__ W, int K,
                            int8_t* __restrict__ out, float* __restrict__ dq) {
    __shared__ float red[256];
    const int row = blockIdx.x, tid = threadIdx.x;
    const float* src = W + (size_t)row * K;
    float m = 0.f;
    for (int k = tid; k < K; k += 256) m = fmaxf(m, fabsf(src[k]));
    red[tid] = m;
    __syncthreads();
    for (int s = 128; s > 0; s >>= 1) {
        if (tid < s) red[tid] = fmaxf(red[tid], red[tid + s]);
        __syncthreads();
    }
    const float rmax = fmaxf(red[0], 1e-8f);
    const float sc = 127.f / rmax;
    int8_t* dst = out + (size_t)row * K;
    for (int k = tid; k < K; k += 256) {
        int v = __float2int_rn(src[k] * sc);
        v = v > 127 ? 127 : (v < -127 ? -127 : v);
        dst[k] = (int8_t)v;
    }
    if (tid == 0) dq[row] = rmax / (127.f * 127.f);
}

__global__ void temb_kern(const float* __restrict__ Wt, const float* __restrict__ bt,
                          float* __restrict__ temb, float half_dt, int total) {
    const int i = blockIdx.x * blockDim.x + threadIdx.x;
    if (i < total) {
        const int j = i >> 9, n = i & 511;
        temb[i] = (j * half_dt) * Wt[n] + bt[n];
    }
}

__global__ void prep_kern(const float* __restrict__ h, const float* __restrict__ temb0,
                          bf16* __restrict__ x0, bf16* __restrict__ hb, int total) {
    const int i = blockIdx.x * blockDim.x + threadIdx.x;
    if (i < total) {
        const float hv = h[i];
        x0[i] = __float2bfloat16(hv + temb0[i & 511]);
        hb[i] = __float2bfloat16(hv);
    }
}

__global__ void init_sync(unsigned* p, int n) {
    const int i = threadIdx.x;
    for (int k = i; k < n; k += 256) p[k] = 0u;
}

extern "C" void kernel_launch(void* const* d_in, const int* in_sizes, int n_in,
                              void* d_out, int out_size, void* d_ws, size_t ws_size,
                              hipStream_t stream) {
    const float* h_in = (const float*)d_in[0];
    const float* W1 = (const float*)d_in[1];
    const float* b1 = (const float*)d_in[2];
    const float* W2 = (const float*)d_in[3];
    const float* b2 = (const float*)d_in[4];
    const float* W3 = (const float*)d_in[5];
    const float* b3 = (const float*)d_in[6];
    const float* Wt = (const float*)d_in[7];
    const float* bt = (const float*)d_in[8];
    const int B = 8192, H = 512, H2 = 1024, NS = 10;
    const float dt = 1.f / NS;

    char* ws = (char*)d_ws;
    auto alloc = [&](size_t bytes) {
        char* p = ws;
        ws += (bytes + 255) & ~(size_t)255;
        return p;
    };
    unsigned* sync = (unsigned*)alloc((8 * 32 + 32) * 4);  // partials + master
    bf16* W1b = (bf16*)alloc((size_t)H2 * H * 2);
    int8_t* W2i = (int8_t*)alloc((size_t)H2 * H2);
    float* dq   = (float*)alloc((size_t)H2 * 4);
    bf16* W3b = (bf16*)alloc((size_t)H * H2 * 2);
    bf16* x0b = (bf16*)alloc((size_t)B * H * 2);
    int8_t* x1i = (int8_t*)alloc((size_t)B * H2);
    bf16* x2b = (bf16*)alloc((size_t)B * H2 * 2);
    bf16* kacc = (bf16*)alloc((size_t)B * H * 2);
    bf16* hb   = (bf16*)alloc((size_t)B * H * 2);
    float* temb = (float*)alloc((size_t)21 * H * 4);
    float* hbuf = (float*)d_out;   // fp32 h state lives in d_out

    unsigned* part = sync;             // 8 counters, stride 32 u32 (128 B)
    unsigned* master = sync + 8 * 32;

    init_sync<<<1, 256, 0, stream>>>(sync, 8 * 32 + 1);
    {
        int n = H2 * H;
        f2b_kern<<<(n + 255) / 256, 256, 0, stream>>>(W1, W1b, n);
        quantW2_row<<<H2, 256, 0, stream>>>(W2, H2, W2i, dq);
        n = H * H2;
        f2b_kern<<<(n + 255) / 256, 256, 0, stream>>>(W3, W3b, n);
    }
    {
        const int total = 21 * H;
        temb_kern<<<(total + 255) / 256, 256, 0, stream>>>(Wt, bt, temb, dt * 0.5f, total);
    }
    {
        const int total = B * H;
        prep_kern<<<(total + 255) / 256, 256, 0, stream>>>(h_in, temb, x0b, hb, total);
    }

    ode_persistent<<<512, 256, 0, stream>>>(W1b, W2i, dq, W3b, b1, b2, b3, temb,
                                            x0b, x1i, x2b, kacc, hb, h_in, hbuf,
                                            part, master);
}

// Round 11
// 9923.721 us; speedup vs baseline: 1.5862x; 1.5862x over previous
//
#include <hip/hip_runtime.h>
#include <hip/hip_bf16.h>
#include <math.h>
#include <stdint.h>

using bf16 = __hip_bfloat16;
typedef __attribute__((ext_vector_type(8))) short short8;   // 8 bf16 (MFMA A/B frag)
typedef __attribute__((ext_vector_type(4))) float floatx4;  // MFMA C/D frag (f32)
typedef __attribute__((ext_vector_type(4))) int int4v;      // i8 K=64 frag / i32 acc

typedef const __attribute__((address_space(1))) void* gptr_t;
typedef __attribute__((address_space(3))) void* lptr_t;

__device__ __forceinline__ void load_lds16(const void* g, void* l) {
    __builtin_amdgcn_global_load_lds((gptr_t)(uintptr_t)g, (lptr_t)(uintptr_t)l, 16, 0, 0);
}

// wait until at most N vector-memory ops outstanding (gfx9 6-bit vmcnt split)
#define WAIT_VM(n) __builtin_amdgcn_s_waitcnt(0x0F70 | ((n) & 15) | (((n) >> 4) << 14))

__device__ __forceinline__ float fast_tanh(float x) {
    float e = __expf(2.f * x);
    return 1.f - 2.f / (e + 1.f);
}

// ---------------------------------------------------------------------------
// Grid barrier, r10 post-mortem fix. r10 spun with ACQUIRE loads: on gfx950
// an agent-scope acquire emits buffer_inv (full local-L2 invalidate, since
// per-XCD L2s are not the coherence point) -> millions of L2 invalidations/s
// chipwide -> every staged tile refetched from L3/HBM (FETCH 7.3 GB vs 2.5,
// 130 us/phase vs 10.5). Fix: fences ONCE per barrier, relaxed spin loads
// (no invalidate), s_sleep backoff. This is the rocPRIM grid-sync pattern.
// Monotonic counters: no reset race. 512 blocks co-resident by construction
// (64 KB LDS + launch_bounds(256,2) = exactly 2 blocks/CU).
// ---------------------------------------------------------------------------
__device__ __forceinline__ void gsync(unsigned* part, unsigned* master, int bar, int b) {
    __syncthreads();
    if (threadIdx.x == 0) {
        // release once: write back this block's phase output to the
        // coherence point (L2 -> L3) before signalling arrival.
        __builtin_amdgcn_fence(__ATOMIC_RELEASE, "agent");
        unsigned* p = part + (b & 7) * 32;
        unsigned old = __hip_atomic_fetch_add(p, 1u, __ATOMIC_RELAXED,
                                              __HIP_MEMORY_SCOPE_AGENT);
        if (old == (unsigned)(64 * bar - 1))
            __hip_atomic_fetch_add(master, 1u, __ATOMIC_RELAXED,
                                   __HIP_MEMORY_SCOPE_AGENT);
        while (__hip_atomic_load(master, __ATOMIC_RELAXED,
                                 __HIP_MEMORY_SCOPE_AGENT) < (unsigned)(8 * bar))
            __builtin_amdgcn_s_sleep(8);
        // acquire once: invalidate stale L1/L2 before reading peers' output.
        __builtin_amdgcn_fence(__ATOMIC_ACQUIRE, "agent");
    }
    __syncthreads();
}

// ---------------------------------------------------------------------------
// Phase 1 (r9 gemm_tanh4): x1i = i8(tanh(x0·W1^T + b1) * 127)
// bf16 core, 128x128 tile, 4 waves, dbuf 2x(16+16) KB, WAIT_VM(8), XCD swizzle.
// ---------------------------------------------------------------------------
__device__ void phase_l1(int b, char* smem, const bf16* __restrict__ A,
                         const bf16* __restrict__ W, const float* __restrict__ bias,
                         int8_t* __restrict__ out) {
    constexpr int MT = 4, NT = 4;
    const int K = 512, N = 1024;
    bf16* lA = (bf16*)smem;              // [2][128*64]
    bf16* lB = (bf16*)(smem + 32768);    // [2][128*64]

    const int xcd = b & 7, j = b >> 3;
    const int bx = j & 7;
    const int by = xcd + 8 * (j >> 3);

    const int tid  = threadIdx.x;
    const int lane = tid & 63;
    const int w    = tid >> 6;
    const int wr   = w >> 1, wc = w & 1;
    const int quad = lane >> 4, l16 = lane & 15;
    const int brow = by * 128, bcol = bx * 128;

    const bf16* gA[4]; const bf16* gW[4]; int lq[4];
#pragma unroll
    for (int jj = 0; jj < 4; ++jj) {
        const int q = tid + jj * 256;
        const int r = q >> 3, s = (q & 7) ^ (r & 7);
        gA[jj] = A + (size_t)(brow + r) * K + s * 8;
        gW[jj] = W + (size_t)(bcol + r) * K + s * 8;
        lq[jj] = q * 8;
    }

    floatx4 acc[MT][NT];
    const floatx4 zero = {0.f, 0.f, 0.f, 0.f};
#pragma unroll
    for (int mt = 0; mt < MT; ++mt)
#pragma unroll
        for (int nt = 0; nt < NT; ++nt) acc[mt][nt] = zero;

    const int arow0 = wr * 64 + l16;
    const int brow0 = wc * 64 + l16;
    const int x7 = l16 & 7;

    const int nIter = K / 64;  // 8
#pragma unroll
    for (int jj = 0; jj < 4; ++jj) load_lds16(gA[jj], lA + lq[jj]);
#pragma unroll
    for (int jj = 0; jj < 4; ++jj) load_lds16(gW[jj], lB + lq[jj]);

    for (int kt = 0; kt < nIter; ++kt) {
        const int cur = kt & 1;
        if (kt + 1 < nIter) {
#pragma unroll
            for (int jj = 0; jj < 4; ++jj)
                load_lds16(gA[jj] + (kt + 1) * 64, lA + (cur ^ 1) * 8192 + lq[jj]);
#pragma unroll
            for (int jj = 0; jj < 4; ++jj)
                load_lds16(gW[jj] + (kt + 1) * 64, lB + (cur ^ 1) * 8192 + lq[jj]);
            WAIT_VM(8);
        } else {
            WAIT_VM(0);
        }
        __builtin_amdgcn_s_barrier();

#pragma unroll
        for (int kk = 0; kk < 2; ++kk) {
            const int sw = ((kk * 4 + quad) ^ x7) * 8;
            short8 af[MT], bfr[NT];
#pragma unroll
            for (int mt = 0; mt < MT; ++mt)
                af[mt] = *(const short8*)(lA + cur * 8192 + (arow0 + mt * 16) * 64 + sw);
#pragma unroll
            for (int nt = 0; nt < NT; ++nt)
                bfr[nt] = *(const short8*)(lB + cur * 8192 + (brow0 + nt * 16) * 64 + sw);
#pragma unroll
            for (int mt = 0; mt < MT; ++mt)
#pragma unroll
                for (int nt = 0; nt < NT; ++nt)
                    acc[mt][nt] = __builtin_amdgcn_mfma_f32_16x16x32_bf16(
                        af[mt], bfr[nt], acc[mt][nt], 0, 0, 0);
        }
        __builtin_amdgcn_s_barrier();
    }

    const int m0 = brow + wr * 64 + quad * 4;
    const int n0 = bcol + wc * 64 + l16;
#pragma unroll
    for (int mt = 0; mt < MT; ++mt)
#pragma unroll
        for (int nt = 0; nt < NT; ++nt) {
            const int n = n0 + nt * 16;
            const float bb = bias[n];
#pragma unroll
            for (int i = 0; i < 4; ++i) {
                const int m = m0 + mt * 16 + i;
                const float t = fast_tanh(acc[mt][nt][i] + bb);
                out[(size_t)m * N + n] = (int8_t)__float2int_rn(t * 127.f);
            }
        }
}

// ---------------------------------------------------------------------------
// Phase 2 (r9 gemm_tanh_i8): x2b = bf16(tanh(acc*dq[n] + b2))
// i8 core, K=1024, 128-B rows, XOR-8 on 16-B chunks, dbuf 2x(16+16) KB.
// ---------------------------------------------------------------------------
__device__ void phase_l2(int b, char* smem, const int8_t* __restrict__ A,
                         const int8_t* __restrict__ W, const float* __restrict__ dq,
                         const float* __restrict__ bias, bf16* __restrict__ out) {
    constexpr int MT = 4, NT = 4;
    const int K = 1024, N = 1024;
    int8_t* lA = (int8_t*)smem;             // [2][128*128]
    int8_t* lB = (int8_t*)(smem + 32768);   // [2][128*128]

    const int xcd = b & 7, j = b >> 3;
    const int bx = j & 7;
    const int by = xcd + 8 * (j >> 3);

    const int tid  = threadIdx.x;
    const int lane = tid & 63;
    const int w    = tid >> 6;
    const int wr   = w >> 1, wc = w & 1;
    const int quad = lane >> 4, l16 = lane & 15;
    const int brow = by * 128, bcol = bx * 128;

    const int8_t* gA[4]; const int8_t* gW[4]; int lq[4];
#pragma unroll
    for (int jj = 0; jj < 4; ++jj) {
        const int q = tid + jj * 256;
        const int r = q >> 3, s = (q & 7) ^ (r & 7);
        gA[jj] = A + (size_t)(brow + r) * K + s * 16;
        gW[jj] = W + (size_t)(bcol + r) * K + s * 16;
        lq[jj] = q * 16;
    }

    int4v acc[MT][NT];
    const int4v izero = {0, 0, 0, 0};
#pragma unroll
    for (int mt = 0; mt < MT; ++mt)
#pragma unroll
        for (int nt = 0; nt < NT; ++nt) acc[mt][nt] = izero;

    const int arow0 = wr * 64 + l16;
    const int brow0 = wc * 64 + l16;
    const int x7 = l16 & 7;

    const int nIter = K / 128;  // 8
#pragma unroll
    for (int jj = 0; jj < 4; ++jj) load_lds16(gA[jj], lA + lq[jj]);
#pragma unroll
    for (int jj = 0; jj < 4; ++jj) load_lds16(gW[jj], lB + lq[jj]);

    for (int kt = 0; kt < nIter; ++kt) {
        const int cur = kt & 1;
        if (kt + 1 < nIter) {
#pragma unroll
            for (int jj = 0; jj < 4; ++jj)
                load_lds16(gA[jj] + (kt + 1) * 128, lA + (cur ^ 1) * 16384 + lq[jj]);
#pragma unroll
            for (int jj = 0; jj < 4; ++jj)
                load_lds16(gW[jj] + (kt + 1) * 128, lB + (cur ^ 1) * 16384 + lq[jj]);
            WAIT_VM(8);
        } else {
            WAIT_VM(0);
        }
        __builtin_amdgcn_s_barrier();

#pragma unroll
        for (int kk = 0; kk < 2; ++kk) {
            const int sw = ((kk * 4 + quad) ^ x7) * 16;
            int4v af[MT], bfr[NT];
#pragma unroll
            for (int mt = 0; mt < MT; ++mt)
                af[mt] = *(const int4v*)(lA + cur * 16384 + (arow0 + mt * 16) * 128 + sw);
#pragma unroll
            for (int nt = 0; nt < NT; ++nt)
                bfr[nt] = *(const int4v*)(lB + cur * 16384 + (brow0 + nt * 16) * 128 + sw);
#pragma unroll
            for (int mt = 0; mt < MT; ++mt)
#pragma unroll
                for (int nt = 0; nt < NT; ++nt)
                    acc[mt][nt] = __builtin_amdgcn_mfma_i32_16x16x64_i8(
                        af[mt], bfr[nt], acc[mt][nt], 0, 0, 0);
        }
        __builtin_amdgcn_s_barrier();
    }

    const int m0 = brow + wr * 64 + quad * 4;
    const int n0 = bcol + wc * 64 + l16;
#pragma unroll
    for (int mt = 0; mt < MT; ++mt)
#pragma unroll
        for (int nt = 0; nt < NT; ++nt) {
            const int n = n0 + nt * 16;
            const float bb = bias[n];
            const float dqn = dq[n];
#pragma unroll
            for (int i = 0; i < 4; ++i) {
                const int m = m0 + mt * 16 + i;
                out[(size_t)m * N + n] =
                    __float2bfloat16(fast_tanh((float)acc[mt][nt][i] * dqn + bb));
            }
        }
}

// ---------------------------------------------------------------------------
// Phase 3 (r9 gemm_k, one 64x64 tile): RK4-fused L3 GEMM, K=1024.
// Single-buffered 2-barrier core (memory-bound; ~its floor). 16 KB LDS.
// ---------------------------------------------------------------------------
__device__ void phase_l3_tile(int T, char* smem, const bf16* __restrict__ A,
                              const bf16* __restrict__ W, const float* __restrict__ bias,
                              bf16* __restrict__ kacc, const bf16* __restrict__ hb_src,
                              const float* __restrict__ h_src, float* __restrict__ h_out,
                              bf16* __restrict__ hb_out, bf16* __restrict__ x0_out,
                              const float* __restrict__ temb, float alpha, float dt6,
                              int mode) {
    constexpr int MT = 2, NT = 2;
    const int K = 1024;
    bf16* lA = (bf16*)smem;             // 8 KB
    bf16* lB = (bf16*)(smem + 8192);    // 8 KB

    const int xcd = T & 7, j = T >> 3;
    const int bx = j & 7;
    const int by = xcd + 8 * (j >> 3);
    const int brow = by * 64, bcol = bx * 64;

    const int tid  = threadIdx.x;
    const int lane = tid & 63;
    const int w    = tid >> 6;
    const int wr   = w >> 1, wc = w & 1;
    const int quad = lane >> 4, l16 = lane & 15;

    const bf16* gA[2]; const bf16* gW[2];
    bf16* lAd[2]; bf16* lBd[2];
#pragma unroll
    for (int jj = 0; jj < 2; ++jj) {
        const int q = tid + jj * 256;
        const int r = q >> 3, s = (q & 7) ^ (r & 7);
        gA[jj]  = A + (size_t)(brow + r) * K + s * 8;
        gW[jj]  = W + (size_t)(bcol + r) * K + s * 8;
        lAd[jj] = lA + q * 8;
        lBd[jj] = lB + q * 8;
    }

    floatx4 acc[MT][NT];
    const floatx4 zero = {0.f, 0.f, 0.f, 0.f};
#pragma unroll
    for (int mt = 0; mt < MT; ++mt)
#pragma unroll
        for (int nt = 0; nt < NT; ++nt) acc[mt][nt] = zero;

    const int arow = wr * 32 + l16;
    const int brw  = wc * 32 + l16;
    const int x7   = l16 & 7;

    const int nIter = K / 64;
    for (int kt = 0; kt < nIter; ++kt) {
#pragma unroll
        for (int jj = 0; jj < 2; ++jj) load_lds16(gA[jj], lAd[jj]);
#pragma unroll
        for (int jj = 0; jj < 2; ++jj) load_lds16(gW[jj], lBd[jj]);
        __syncthreads();

#pragma unroll
        for (int kk = 0; kk < 2; ++kk) {
            const int sw = ((kk * 4 + quad) ^ x7) * 8;
            short8 af[MT], bfr[NT];
#pragma unroll
            for (int mt = 0; mt < MT; ++mt)
                af[mt] = *(const short8*)(lA + (arow + mt * 16) * 64 + sw);
#pragma unroll
            for (int nt = 0; nt < NT; ++nt)
                bfr[nt] = *(const short8*)(lB + (brw + nt * 16) * 64 + sw);
#pragma unroll
            for (int mt = 0; mt < MT; ++mt)
#pragma unroll
                for (int nt = 0; nt < NT; ++nt)
                    acc[mt][nt] = __builtin_amdgcn_mfma_f32_16x16x32_bf16(
                        af[mt], bfr[nt], acc[mt][nt], 0, 0, 0);
        }
        __syncthreads();

#pragma unroll
        for (int jj = 0; jj < 2; ++jj) gA[jj] += 64;
#pragma unroll
        for (int jj = 0; jj < 2; ++jj) gW[jj] += 64;
    }

    const int m0 = brow + wr * 32 + quad * 4;
    const int n0 = bcol + wc * 32 + l16;
#pragma unroll
    for (int mt = 0; mt < MT; ++mt)
#pragma unroll
        for (int nt = 0; nt < NT; ++nt) {
            const int n = n0 + nt * 16;
            const float bb = bias[n];
            const float te = temb[n];
#pragma unroll
            for (int i = 0; i < 4; ++i) {
                const int m = m0 + mt * 16 + i;
                const size_t idx = (size_t)m * 512 + n;
                const float kv = acc[mt][nt][i] + bb;
                if (mode == 0) {
                    kacc[idx] = __float2bfloat16(kv);
                    x0_out[idx] = __float2bfloat16(
                        __bfloat162float(hb_src[idx]) + alpha * kv + te);
                } else if (mode == 1) {
                    kacc[idx] = __float2bfloat16(__bfloat162float(kacc[idx]) + 2.f * kv);
                    x0_out[idx] = __float2bfloat16(
                        __bfloat162float(hb_src[idx]) + alpha * kv + te);
                } else {
                    const float hn = h_src[idx] + dt6 * (__bfloat162float(kacc[idx]) + kv);
                    h_out[idx] = hn;
                    hb_out[idx] = __float2bfloat16(hn);
                    if (x0_out) x0_out[idx] = __float2bfloat16(hn + te);
                }
            }
        }
}

// ---------------------------------------------------------------------------
// Persistent kernel: 10 RK4 steps x 4 evals x 3 GEMM phases, grid barriers
// between phases. 512 blocks, 64 KB LDS, 2 blocks/CU -> all co-resident.
// ---------------------------------------------------------------------------
__global__ void __launch_bounds__(256, 2)
ode_persistent(const bf16* __restrict__ W1b, const int8_t* __restrict__ W2i,
               const float* __restrict__ dq, const bf16* __restrict__ W3b,
               const float* __restrict__ b1, const float* __restrict__ b2,
               const float* __restrict__ b3, const float* __restrict__ temb,
               bf16* __restrict__ x0b, int8_t* __restrict__ x1i,
               bf16* __restrict__ x2b, bf16* __restrict__ kacc,
               bf16* __restrict__ hb, const float* __restrict__ h_in,
               float* __restrict__ hbuf, unsigned* __restrict__ part,
               unsigned* __restrict__ master) {
    __shared__ alignas(16) char smem[65536];
    const int b = blockIdx.x;
    const float dt = 0.1f;
    int bar = 0;

    for (int s = 0; s < 10; ++s) {
        const float* hs = (s == 0) ? h_in : hbuf;
        const float* tmid = temb + (size_t)(2 * s + 1) * 512;
        const float* tend = temb + (size_t)(2 * s + 2) * 512;
        for (int e = 0; e < 4; ++e) {
            phase_l1(b, smem, x0b, W1b, b1, x1i);
            gsync(part, master, ++bar, b);
            phase_l2(b, smem, x1i, W2i, dq, b2, x2b);
            gsync(part, master, ++bar, b);
            const float* te; float alpha, dt6; int mode;
            bf16* x0o = x0b;
            if (e == 0)      { mode = 0; alpha = dt * 0.5f; dt6 = 0.f; te = tmid; }
            else if (e == 1) { mode = 1; alpha = dt * 0.5f; dt6 = 0.f; te = tmid; }
            else if (e == 2) { mode = 1; alpha = dt;        dt6 = 0.f; te = tend; }
            else             { mode = 2; alpha = 0.f; dt6 = dt / 6.f; te = tend;
                               if (s == 9) x0o = nullptr; }
#pragma unroll
            for (int t = 0; t < 2; ++t)
                phase_l3_tile(b + 512 * t, smem, x2b, W3b, b3, kacc, hb, hs,
                              hbuf, hb, x0o, te, alpha, dt6, mode);
            gsync(part, master, ++bar, b);
        }
    }
}

// ------------------------------ setup kernels ------------------------------
__global__ void f2b_kern(const float* __restrict__ src, bf16* __restrict__ dst, int n) {
    const int i = blockIdx.x * blockDim.x + threadIdx.x;
    if (i < n) dst[i] = __float2bfloat16(src[i]);
}

__global__ void quantW2_row(const float* __restrict__ W, int K,
                            int8_t* __restrict__ out, float* __restrict__ dq) {
    __shared__ float red[256];
    const int row = blockIdx.x, tid = threadIdx.x;
    const float* src = W + (size_t)row * K;
    float m = 0.f;
    for (int k = tid; k < K; k += 256) m = fmaxf(m, fabsf(src[k]));
    red[tid] = m;
    __syncthreads();
    for (int s = 128; s > 0; s >>= 1) {
        if (tid < s) red[tid] = fmaxf(red[tid], red[tid + s]);
        __syncthreads();
    }
    const float rmax = fmaxf(red[0], 1e-8f);
    const float sc = 127.f / rmax;
    int8_t* dst = out + (size_t)row * K;
    for (int k = tid; k < K; k += 256) {
        int v = __float2int_rn(src[k] * sc);
        v = v > 127 ? 127 : (v < -127 ? -127 : v);
        dst[k] = (int8_t)v;
    }
    if (tid == 0) dq[row] = rmax / (127.f * 127.f);
}

__global__ void temb_kern(const float* __restrict__ Wt, const float* __restrict__ bt,
                          float* __restrict__ temb, float half_dt, int total) {
    const int i = blockIdx.x * blockDim.x + threadIdx.x;
    if (i < total) {
        const int j = i >> 9, n = i & 511;
        temb[i] = (j * half_dt) * Wt[n] + bt[n];
    }
}

__global__ void prep_kern(const float* __restrict__ h, const float* __restrict__ temb0,
                          bf16* __restrict__ x0, bf16* __restrict__ hb, int total) {
    const int i = blockIdx.x * blockDim.x + threadIdx.x;
    if (i < total) {
        const float hv = h[i];
        x0[i] = __float2bfloat16(hv + temb0[i & 511]);
        hb[i] = __float2bfloat16(hv);
    }
}

__global__ void init_sync(unsigned* p, int n) {
    const int i = threadIdx.x;
    for (int k = i; k < n; k += 256) p[k] = 0u;
}

extern "C" void kernel_launch(void* const* d_in, const int* in_sizes, int n_in,
                              void* d_out, int out_size, void* d_ws, size_t ws_size,
                              hipStream_t stream) {
    const float* h_in = (const float*)d_in[0];
    const float* W1 = (const float*)d_in[1];
    const float* b1 = (const float*)d_in[2];
    const float* W2 = (const float*)d_in[3];
    const float* b2 = (const float*)d_in[4];
    const float* W3 = (const float*)d_in[5];
    const float* b3 = (const float*)d_in[6];
    const float* Wt = (const float*)d_in[7];
    const float* bt = (const float*)d_in[8];
    const int B = 8192, H = 512, H2 = 1024, NS = 10;
    const float dt = 1.f / NS;

    char* ws = (char*)d_ws;
    auto alloc = [&](size_t bytes) {
        char* p = ws;
        ws += (bytes + 255) & ~(size_t)255;
        return p;
    };
    unsigned* sync = (unsigned*)alloc((8 * 32 + 32) * 4);  // partials + master
    bf16* W1b = (bf16*)alloc((size_t)H2 * H * 2);
    int8_t* W2i = (int8_t*)alloc((size_t)H2 * H2);
    float* dq   = (float*)alloc((size_t)H2 * 4);
    bf16* W3b = (bf16*)alloc((size_t)H * H2 * 2);
    bf16* x0b = (bf16*)alloc((size_t)B * H * 2);
    int8_t* x1i = (int8_t*)alloc((size_t)B * H2);
    bf16* x2b = (bf16*)alloc((size_t)B * H2 * 2);
    bf16* kacc = (bf16*)alloc((size_t)B * H * 2);
    bf16* hb   = (bf16*)alloc((size_t)B * H * 2);
    float* temb = (float*)alloc((size_t)21 * H * 4);
    float* hbuf = (float*)d_out;   // fp32 h state lives in d_out

    unsigned* part = sync;             // 8 counters, stride 32 u32 (128 B)
    unsigned* master = sync + 8 * 32;

    init_sync<<<1, 256, 0, stream>>>(sync, 8 * 32 + 1);
    {
        int n = H2 * H;
        f2b_kern<<<(n + 255) / 256, 256, 0, stream>>>(W1, W1b, n);
        quantW2_row<<<H2, 256, 0, stream>>>(W2, H2, W2i, dq);
        n = H * H2;
        f2b_kern<<<(n + 255) / 256, 256, 0, stream>>>(W3, W3b, n);
    }
    {
        const int total = 21 * H;
        temb_kern<<<(total + 255) / 256, 256, 0, stream>>>(Wt, bt, temb, dt * 0.5f, total);
    }
    {
        const int total = B * H;
        prep_kern<<<(total + 255) / 256, 256, 0, stream>>>(h_in, temb, x0b, hb, total);
    }

    ode_persistent<<<512, 256, 0, stream>>>(W1b, W2i, dq, W3b, b1, b2, b3, temb,
                                            x0b, x1i, x2b, kacc, hb, h_in, hbuf,
                                            part, master);
}